// Round 5
// baseline (321.558 us; speedup 1.0000x reference)
//
#include <hip/hip_runtime.h>

// Problem constants (fixed by setup_inputs)
#define M_DIM 8192      // 4*2048
#define N_DIM 4096      // out_f
#define K_DIM 4096      // in_f
#define GROUPS_PER_ROW 128
#define NT (K_DIM / 64) // 64 K-tiles of BK=64

typedef short bf16x8 __attribute__((ext_vector_type(8)));
typedef float f32x16 __attribute__((ext_vector_type(16)));
typedef unsigned short u16x8 __attribute__((ext_vector_type(8)));

__device__ __forceinline__ unsigned short f2bf(float f) {
    unsigned int u = __float_as_uint(f);
    u += 0x7fffu + ((u >> 16) & 1u);   // round-to-nearest-even
    return (unsigned short)(u >> 16);
}

typedef const __attribute__((address_space(1))) void gvoid_t;
typedef __attribute__((address_space(3))) void lvoid_t;
__device__ __forceinline__ void gload_lds16(const void* g, void* l) {
    __builtin_amdgcn_global_load_lds((gvoid_t*)g, (lvoid_t*)l, 16, 0, 0);
}

// ---------- pass 1: dequantize weight -> bf16 [N][K] ----------
__global__ __launch_bounds__(256) void dequant_kernel(
        const float* __restrict__ w, const float* __restrict__ value,
        const float* __restrict__ mins, const float* __restrict__ maxs,
        unsigned short* __restrict__ wq) {
    int g = blockIdx.x * 256 + threadIdx.x;
    const float4* wp = reinterpret_cast<const float4*>(w + (size_t)g * 32);
    const float4* vp = reinterpret_cast<const float4*>(value + (size_t)g * 32);
    float4 wv[8], vv[8];
    #pragma unroll
    for (int j = 0; j < 8; j++) { wv[j] = wp[j]; vv[j] = vp[j]; }
    float mn = wv[0].x, mx = wv[0].x;
    #pragma unroll
    for (int j = 0; j < 8; j++) {
        mn = fminf(mn, fminf(fminf(wv[j].x, wv[j].y), fminf(wv[j].z, wv[j].w)));
        mx = fmaxf(mx, fmaxf(fmaxf(wv[j].x, wv[j].y), fmaxf(wv[j].z, wv[j].w)));
    }
    float w_min = mn * mins[g];
    float w_max = mx * maxs[g];
    float scale = fmaxf((w_max - w_min) * (1.0f / 255.0f), 1e-8f);
    float zp    = -w_min / scale;
    float rs    = 1.0f / scale;
    unsigned short ob[32];
    #pragma unroll
    for (int j = 0; j < 8; j++) {
        const float* wf = &wv[j].x;
        const float* vf = &vv[j].x;
        #pragma unroll
        for (int c = 0; c < 4; c++) {
            float ws_ = wf[c] * rs + zp + vf[c];
            float q   = fminf(fmaxf(rintf(ws_), 0.0f), 255.0f);
            ob[j * 4 + c] = f2bf(scale * (q - zp));
        }
    }
    u16x8* op = reinterpret_cast<u16x8*>(wq + (size_t)g * 32);
    #pragma unroll
    for (int j = 0; j < 4; j++) {
        u16x8 v;
        #pragma unroll
        for (int c = 0; c < 8; c++) v[c] = ob[j * 8 + c];
        op[j] = v;
    }
}

// ---------- pass 2: x f32 -> bf16 ----------
__global__ __launch_bounds__(256) void xconv_kernel(
        const float* __restrict__ x, unsigned short* __restrict__ xb) {
    int t = blockIdx.x * 256 + threadIdx.x;
    const float4* xp = reinterpret_cast<const float4*>(x) + (size_t)t * 2;
    float4 a = xp[0], b = xp[1];
    u16x8 v;
    v[0] = f2bf(a.x); v[1] = f2bf(a.y); v[2] = f2bf(a.z); v[3] = f2bf(a.w);
    v[4] = f2bf(b.x); v[5] = f2bf(b.y); v[6] = f2bf(b.z); v[7] = f2bf(b.w);
    reinterpret_cast<u16x8*>(xb)[t] = v;
}

// ---------- pass 3: 256x256 8-wave 3-phase 32x32x16 MFMA GEMM-BT + bias ----------
// C[m][n] = sum_k A[m][k]*B[n][k] + bias[n]
// LDS per 64KB buffer: A [2 half(128r)][2 kk-panel][128][64B] at 0, B same at +32KB
// — IDENTICAL physical layout + staging swizzle (bit9->bit5) as the verified
// round-2/4 kernel. Read side: full intra-row offset assembled BEFORE the XOR
// (round-3 bug was XOR-then-ADD carry on bit 5).
__global__ __launch_bounds__(512, 2) void gemm_kernel(
        const unsigned short* __restrict__ A, const unsigned short* __restrict__ B,
        const float* __restrict__ bias, float* __restrict__ C) {
    __shared__ __align__(128) char lds[131072];

    const int tid  = threadIdx.x;
    const int lane = tid & 63;
    const int w    = tid >> 6;          // 0..7
    const int wr   = w >> 2;            // 0..1 (M split: 128 rows)
    const int wc   = w & 3;             // 0..3 (N split: 64 cols)
    const int l31  = lane & 31, l5 = lane >> 5;

    // T1: bijective XCD swizzle (grid=512, 512%8==0)
    const int bid = blockIdx.x;
    const int swz = (bid & 7) * 64 + (bid >> 3);
    const int bm  = swz >> 4;           // 0..31
    const int bn  = swz & 15;           // 0..15

    // read-side swizzle mask: row bit3 (= l31 bit3) -> addr bit5
    const int amask = (l31 & 8) << 2;   // bit 5
    const int ib    = l5 * 16;          // bit 4 (k-sub within 16-k fragment)

    // region bases (byte offsets into half-buffer)
    const int aoff = wr * 16384 + l31 * 64;
    const int boff = 32768 + (wc >> 1) * 16384 + (wc & 1) * 4096 + l31 * 64;

    // staging: linear 16B chunks; source address inverse-swizzled (bit9->bit5,
    // involution) — identical to round-2/4 verified code
    const int c0  = tid * 16;
    const int c1  = 8192 + tid * 16;
    const int lb0 = c0 ^ (((c0 >> 9) & 1) << 5);
    const int lb1 = c1 ^ (((c1 >> 9) & 1) << 5);
    const int so0 = ((lb0 >> 6) & 127) * (K_DIM * 2) + (lb0 >> 13) * 64 + (lb0 & 63);
    const int so1 = ((lb1 >> 6) & 127) * (K_DIM * 2) + (lb1 >> 13) * 64 + (lb1 & 63);

    const char* srcA0 = (const char*)A + (size_t)(bm * 256 +   0) * (K_DIM * 2);
    const char* srcA1 = (const char*)A + (size_t)(bm * 256 + 128) * (K_DIM * 2);
    const char* srcB0 = (const char*)B + (size_t)(bn * 256 +   0) * (K_DIM * 2);
    const char* srcB1 = (const char*)B + (size_t)(bn * 256 + 128) * (K_DIM * 2);

    char* ldsc = (char*)lds;
    auto STAGE = [&](const char* src, int tt, int regionOff) {
        gload_lds16(src + (size_t)tt * 128 + so0, ldsc + regionOff + c0);
        gload_lds16(src + (size_t)tt * 128 + so1, ldsc + regionOff + c1);
    };

    f32x16 acc[4][2] = {};          // [mb 0..3][nb 0..1] = 128 acc regs
    bf16x8 af[2][4], bfA[4], bfB[4];

    // fragment byte offset helper (compile-time kb):
    //   FR(kb) = (kb>>1)*8192 + (((kb&1)*32) ^ amask) + ib
    // full A addr(mb,kb)  = bo + aoff + mb*2048 + FR(kb)
    // full B addr(nb,kb)  = bo + boff + nb*2048 + FR(kb)

    // prologue: tile0 all 4 half-tiles -> buf0; tile1 A halves -> buf1
    STAGE(srcA0, 0, 0);
    STAGE(srcA1, 0, 16384);
    STAGE(srcB0, 0, 32768);
    STAGE(srcB1, 0, 49152);
    STAGE(srcA0, 1, 65536);
    STAGE(srcA1, 1, 65536 + 16384);
    asm volatile("s_waitcnt vmcnt(4)" ::: "memory");
    __builtin_amdgcn_s_barrier();
    __builtin_amdgcn_sched_barrier(0);

    #pragma unroll 2
    for (int t = 0; t < NT; ++t) {
        const int bo  = (t & 1) << 16;
        const int bo2 = bo ^ 65536;

        // ---- phase 1: read A(mb0,1)+B(nb0); stage B_lo(t+1); MFMA Q00 ----
        #pragma unroll
        for (int mb = 0; mb < 2; ++mb)
            #pragma unroll
            for (int kb = 0; kb < 4; ++kb)
                af[mb][kb] = *(const bf16x8*)(ldsc + bo + aoff + mb * 2048
                                + (kb >> 1) * 8192 + (((kb & 1) * 32) ^ amask) + ib);
        #pragma unroll
        for (int kb = 0; kb < 4; ++kb)
            bfA[kb] = *(const bf16x8*)(ldsc + bo + boff
                                + (kb >> 1) * 8192 + (((kb & 1) * 32) ^ amask) + ib);
        if (t + 1 < NT) STAGE(srcB0, t + 1, bo2 + 32768);
        __builtin_amdgcn_s_barrier();
        __builtin_amdgcn_sched_barrier(0);
        __builtin_amdgcn_s_setprio(1);
        #pragma unroll
        for (int mb = 0; mb < 2; ++mb)
            #pragma unroll
            for (int kb = 0; kb < 4; ++kb)
                acc[mb][0] = __builtin_amdgcn_mfma_f32_32x32x16_bf16(
                    af[mb][kb], bfA[kb], acc[mb][0], 0, 0, 0);
        __builtin_amdgcn_s_setprio(0);

        // ---- phase 2: read B(nb1); stage B_hi(t+1); MFMA Q01 ----
        #pragma unroll
        for (int kb = 0; kb < 4; ++kb)
            bfB[kb] = *(const bf16x8*)(ldsc + bo + boff + 2048
                                + (kb >> 1) * 8192 + (((kb & 1) * 32) ^ amask) + ib);
        if (t + 1 < NT) STAGE(srcB1, t + 1, bo2 + 49152);
        __builtin_amdgcn_s_barrier();
        __builtin_amdgcn_sched_barrier(0);
        __builtin_amdgcn_s_setprio(1);
        #pragma unroll
        for (int mb = 0; mb < 2; ++mb)
            #pragma unroll
            for (int kb = 0; kb < 4; ++kb)
                acc[mb][1] = __builtin_amdgcn_mfma_f32_32x32x16_bf16(
                    af[mb][kb], bfB[kb], acc[mb][1], 0, 0, 0);
        __builtin_amdgcn_s_setprio(0);

        // ---- phase 3: read A(mb2,3); stage A_lo+A_hi(t+2); MFMA Q11+Q10; vmcnt ----
        #pragma unroll
        for (int mb = 0; mb < 2; ++mb)
            #pragma unroll
            for (int kb = 0; kb < 4; ++kb)
                af[mb][kb] = *(const bf16x8*)(ldsc + bo + aoff + (mb + 2) * 2048
                                + (kb >> 1) * 8192 + (((kb & 1) * 32) ^ amask) + ib);
        if (t + 2 < NT) {
            STAGE(srcA0, t + 2, bo + 0);
            STAGE(srcA1, t + 2, bo + 16384);
        }
        __builtin_amdgcn_s_barrier();
        __builtin_amdgcn_sched_barrier(0);
        __builtin_amdgcn_s_setprio(1);
        #pragma unroll
        for (int mb = 0; mb < 2; ++mb)
            #pragma unroll
            for (int kb = 0; kb < 4; ++kb)
                acc[mb + 2][1] = __builtin_amdgcn_mfma_f32_32x32x16_bf16(
                    af[mb][kb], bfB[kb], acc[mb + 2][1], 0, 0, 0);
        #pragma unroll
        for (int mb = 0; mb < 2; ++mb)
            #pragma unroll
            for (int kb = 0; kb < 4; ++kb)
                acc[mb + 2][0] = __builtin_amdgcn_mfma_f32_32x32x16_bf16(
                    af[mb][kb], bfA[kb], acc[mb + 2][0], 0, 0, 0);
        __builtin_amdgcn_s_setprio(0);
        if (t + 2 < NT)      { asm volatile("s_waitcnt vmcnt(4)" ::: "memory"); }
        else if (t + 1 < NT) { asm volatile("s_waitcnt vmcnt(0)" ::: "memory"); }
        __builtin_amdgcn_s_barrier();
        __builtin_amdgcn_sched_barrier(0);
    }

    // epilogue: 32x32 C/D layout col=lane&31, row=(reg&3)+8*(reg>>2)+4*(lane>>5)
    float bv[2];
    #pragma unroll
    for (int nb = 0; nb < 2; ++nb)
        bv[nb] = bias[bn * 256 + wc * 64 + nb * 32 + l31];
    #pragma unroll
    for (int mb = 0; mb < 4; ++mb) {
        const int rbase = bm * 256 + wr * 128 + mb * 32 + 4 * l5;
        #pragma unroll
        for (int nb = 0; nb < 2; ++nb) {
            const int col = bn * 256 + wc * 64 + nb * 32 + l31;
            #pragma unroll
            for (int r = 0; r < 16; ++r) {
                const int row = rbase + (r & 3) + 8 * (r >> 2);
                C[(size_t)row * N_DIM + col] = acc[mb][nb][r] + bv[nb];
            }
        }
    }
}

// ---------- fallback (ws too small): slow but correct ----------
__global__ __launch_bounds__(256) void fallback_gemm(
        const float* __restrict__ x, const float* __restrict__ w,
        const float* __restrict__ value, const float* __restrict__ mins,
        const float* __restrict__ maxs, const float* __restrict__ bias,
        float* __restrict__ out) {
    const int n = blockIdx.x;
    __shared__ float wrow[K_DIM];
    const int tid = threadIdx.x;
    if (tid < GROUPS_PER_ROW) {
        const int g = tid;
        const float* wp = w + (size_t)n * K_DIM + g * 32;
        const float* vp = value + (size_t)n * K_DIM + g * 32;
        float tw[32];
        float mn = 1e30f, mx = -1e30f;
        #pragma unroll
        for (int j = 0; j < 32; j++) {
            tw[j] = wp[j]; mn = fminf(mn, tw[j]); mx = fmaxf(mx, tw[j]);
        }
        float wmin = mn * mins[n * GROUPS_PER_ROW + g];
        float wmax = mx * maxs[n * GROUPS_PER_ROW + g];
        float scale = fmaxf((wmax - wmin) * (1.0f / 255.0f), 1e-8f);
        float zp = -wmin / scale;
        #pragma unroll
        for (int j = 0; j < 32; j++) {
            float ws_ = tw[j] / scale + zp + vp[j];
            float q = fminf(fmaxf(rintf(ws_), 0.0f), 255.0f);
            wrow[g * 32 + j] = scale * (q - zp);
        }
    }
    __syncthreads();
    const float bv = bias[n];
    for (int m = tid; m < M_DIM; m += 256) {
        const float4* xr = reinterpret_cast<const float4*>(x + (size_t)m * K_DIM);
        const float4* wr4 = reinterpret_cast<const float4*>(wrow);
        float s = 0.f;
        for (int k = 0; k < K_DIM / 4; k++) {
            float4 a = xr[k], b = wr4[k];
            s += a.x * b.x + a.y * b.y + a.z * b.z + a.w * b.w;
        }
        out[(size_t)m * N_DIM + n] = s + bv;
    }
}

extern "C" void kernel_launch(void* const* d_in, const int* in_sizes, int n_in,
                              void* d_out, int out_size, void* d_ws, size_t ws_size,
                              hipStream_t stream) {
    const float* x     = (const float*)d_in[0];
    const float* ow    = (const float*)d_in[1];
    const float* value = (const float*)d_in[2];
    const float* mins  = (const float*)d_in[3];
    const float* maxs  = (const float*)d_in[4];
    const float* bias  = (const float*)d_in[5];
    float* out = (float*)d_out;

    const size_t xb_bytes = (size_t)M_DIM * K_DIM * 2;
    const size_t wb_bytes = (size_t)N_DIM * K_DIM * 2;

    if (ws_size >= xb_bytes + wb_bytes) {
        unsigned short* xb = (unsigned short*)d_ws;
        unsigned short* wb = (unsigned short*)((char*)d_ws + xb_bytes);

        dequant_kernel<<<(N_DIM * GROUPS_PER_ROW) / 256, 256, 0, stream>>>(
            ow, value, mins, maxs, wb);
        xconv_kernel<<<(M_DIM * K_DIM / 8) / 256, 256, 0, stream>>>(x, xb);
        gemm_kernel<<<(M_DIM / 256) * (N_DIM / 256), 512, 0, stream>>>(
            xb, wb, bias, out);
    } else {
        fallback_gemm<<<N_DIM, 256, 0, stream>>>(x, ow, value, mins, maxs, bias, out);
    }
}

// Round 6
// 312.494 us; speedup vs baseline: 1.0290x; 1.0290x over previous
//
#include <hip/hip_runtime.h>

// Problem constants (fixed by setup_inputs)
#define M_DIM 8192      // 4*2048
#define N_DIM 4096      // out_f
#define K_DIM 4096      // in_f
#define GROUPS_PER_ROW 128
#define NT (K_DIM / 64) // 64 K-tiles of BK=64

typedef short bf16x8 __attribute__((ext_vector_type(8)));
typedef float f32x16 __attribute__((ext_vector_type(16)));
typedef unsigned short u16x8 __attribute__((ext_vector_type(8)));

__device__ __forceinline__ unsigned short f2bf(float f) {
    unsigned int u = __float_as_uint(f);
    u += 0x7fffu + ((u >> 16) & 1u);   // round-to-nearest-even
    return (unsigned short)(u >> 16);
}

typedef const __attribute__((address_space(1))) void gvoid_t;
typedef __attribute__((address_space(3))) void lvoid_t;
__device__ __forceinline__ void gload_lds16(const void* g, void* l) {
    __builtin_amdgcn_global_load_lds((gvoid_t*)g, (lvoid_t*)l, 16, 0, 0);
}

// ---------- pass 1: dequantize weight -> bf16 [N][K] ----------
__global__ __launch_bounds__(256) void dequant_kernel(
        const float* __restrict__ w, const float* __restrict__ value,
        const float* __restrict__ mins, const float* __restrict__ maxs,
        unsigned short* __restrict__ wq) {
    int g = blockIdx.x * 256 + threadIdx.x;
    const float4* wp = reinterpret_cast<const float4*>(w + (size_t)g * 32);
    const float4* vp = reinterpret_cast<const float4*>(value + (size_t)g * 32);
    float4 wv[8], vv[8];
    #pragma unroll
    for (int j = 0; j < 8; j++) { wv[j] = wp[j]; vv[j] = vp[j]; }
    float mn = wv[0].x, mx = wv[0].x;
    #pragma unroll
    for (int j = 0; j < 8; j++) {
        mn = fminf(mn, fminf(fminf(wv[j].x, wv[j].y), fminf(wv[j].z, wv[j].w)));
        mx = fmaxf(mx, fmaxf(fmaxf(wv[j].x, wv[j].y), fmaxf(wv[j].z, wv[j].w)));
    }
    float w_min = mn * mins[g];
    float w_max = mx * maxs[g];
    float scale = fmaxf((w_max - w_min) * (1.0f / 255.0f), 1e-8f);
    float zp    = -w_min / scale;
    float rs    = 1.0f / scale;
    unsigned short ob[32];
    #pragma unroll
    for (int j = 0; j < 8; j++) {
        const float* wf = &wv[j].x;
        const float* vf = &vv[j].x;
        #pragma unroll
        for (int c = 0; c < 4; c++) {
            float ws_ = wf[c] * rs + zp + vf[c];
            float q   = fminf(fmaxf(rintf(ws_), 0.0f), 255.0f);
            ob[j * 4 + c] = f2bf(scale * (q - zp));
        }
    }
    u16x8* op = reinterpret_cast<u16x8*>(wq + (size_t)g * 32);
    #pragma unroll
    for (int j = 0; j < 4; j++) {
        u16x8 v;
        #pragma unroll
        for (int c = 0; c < 8; c++) v[c] = ob[j * 8 + c];
        op[j] = v;
    }
}

// ---------- pass 2: x f32 -> bf16 ----------
__global__ __launch_bounds__(256) void xconv_kernel(
        const float* __restrict__ x, unsigned short* __restrict__ xb) {
    int t = blockIdx.x * 256 + threadIdx.x;
    const float4* xp = reinterpret_cast<const float4*>(x) + (size_t)t * 2;
    float4 a = xp[0], b = xp[1];
    u16x8 v;
    v[0] = f2bf(a.x); v[1] = f2bf(a.y); v[2] = f2bf(a.z); v[3] = f2bf(a.w);
    v[4] = f2bf(b.x); v[5] = f2bf(b.y); v[6] = f2bf(b.z); v[7] = f2bf(b.w);
    reinterpret_cast<u16x8*>(xb)[t] = v;
}

// ---------- pass 3: 256x256 8-wave 3-phase 32x32x16 MFMA GEMM-BT + bias ----------
// C[m][n] = sum_k A[m][k]*B[n][k] + bias[n]
// LDS per 64KB buffer: A [2 half(128r)][2 kk-panel][128 rows][64B] at 0, B at +32KB.
// WIDE swizzle (round-6): phys = L ^ ((L>>9&1)<<4) ^ ((L>>10&1)<<5)
//   = col bits {4,5} XOR row bits {3,4}. Involution; applied BOTH sides.
// Half-wave (32-lane) bank spread: rows 0-7/8-15/16-23/24-31 -> 4 distinct
// 16B slots -> 4 lanes per bank group (the proven-clean 16x16 distribution).
// Read addressing: assemble full col offset, THEN XOR (no ADD after XOR —
// round-3's carry bug class eliminated).
__global__ __launch_bounds__(512, 2) void gemm_kernel(
        const unsigned short* __restrict__ A, const unsigned short* __restrict__ B,
        const float* __restrict__ bias, float* __restrict__ C) {
    __shared__ __align__(128) char lds[131072];

    const int tid  = threadIdx.x;
    const int lane = tid & 63;
    const int w    = tid >> 6;          // 0..7
    const int wr   = w >> 2;            // 0..1 (M split: 128 rows)
    const int wc   = w & 3;             // 0..3 (N split: 64 cols)
    const int l31  = lane & 31, l5 = lane >> 5;

    // T1: bijective XCD swizzle (grid=512, 512%8==0)
    const int bid = blockIdx.x;
    const int swz = (bid & 7) * 64 + (bid >> 3);
    const int bm  = swz >> 4;           // 0..31
    const int bn  = swz & 15;           // 0..15

    // read-side swizzle mask: row bits 3,4 (= l31 bits 3,4) -> col bits 4,5
    const int amask = (l31 & 24) << 1;  // bits 4,5
    const int ib    = l5 * 16;          // k-sub half (bit 4)

    // region bases (byte offsets into half-buffer); row term l31*64 (bits >=6)
    const int aoff = wr * 16384 + l31 * 64;
    const int boff = 32768 + (wc >> 1) * 16384 + (wc & 1) * 4096 + l31 * 64;

    // staging: linear 16B chunks; source address inverse-swizzled
    // (bits 9,10 -> bits 4,5; involution)
    const int c0  = tid * 16;
    const int c1  = 8192 + tid * 16;
    const int lb0 = c0 ^ (((c0 >> 9) & 1) << 4) ^ (((c0 >> 10) & 1) << 5);
    const int lb1 = c1 ^ (((c1 >> 9) & 1) << 4) ^ (((c1 >> 10) & 1) << 5);
    const int so0 = ((lb0 >> 6) & 127) * (K_DIM * 2) + (lb0 >> 13) * 64 + (lb0 & 63);
    const int so1 = ((lb1 >> 6) & 127) * (K_DIM * 2) + (lb1 >> 13) * 64 + (lb1 & 63);

    const char* srcA0 = (const char*)A + (size_t)(bm * 256 +   0) * (K_DIM * 2);
    const char* srcA1 = (const char*)A + (size_t)(bm * 256 + 128) * (K_DIM * 2);
    const char* srcB0 = (const char*)B + (size_t)(bn * 256 +   0) * (K_DIM * 2);
    const char* srcB1 = (const char*)B + (size_t)(bn * 256 + 128) * (K_DIM * 2);

    char* ldsc = (char*)lds;
    auto STAGE = [&](const char* src, int tt, int regionOff) {
        gload_lds16(src + (size_t)tt * 128 + so0, ldsc + regionOff + c0);
        gload_lds16(src + (size_t)tt * 128 + so1, ldsc + regionOff + c1);
    };

    f32x16 acc[4][2] = {};          // [mb 0..3][nb 0..1] = 128 acc regs
    bf16x8 af[2][4], bfA[4], bfB[4];

    // fragment byte offset (compile-time kb):
    //   FR(kb) = (kb>>1)*8192 + (((kb&1)*32 + ib) ^ amask)
    // full addr = bo + {a,b}off + {mb,nb}*2048 + FR(kb)   (all adds disjoint-bit)

    // prologue: tile0 all 4 half-tiles -> buf0; tile1 A halves -> buf1
    STAGE(srcA0, 0, 0);
    STAGE(srcA1, 0, 16384);
    STAGE(srcB0, 0, 32768);
    STAGE(srcB1, 0, 49152);
    STAGE(srcA0, 1, 65536);
    STAGE(srcA1, 1, 65536 + 16384);
    asm volatile("s_waitcnt vmcnt(4)" ::: "memory");
    __builtin_amdgcn_s_barrier();
    __builtin_amdgcn_sched_barrier(0);

    #pragma unroll 2
    for (int t = 0; t < NT; ++t) {
        const int bo  = (t & 1) << 16;
        const int bo2 = bo ^ 65536;

        // ---- phase 1: read A(mb0,1)+B(nb0); stage B_lo(t+1); MFMA Q00 ----
        #pragma unroll
        for (int mb = 0; mb < 2; ++mb)
            #pragma unroll
            for (int kb = 0; kb < 4; ++kb)
                af[mb][kb] = *(const bf16x8*)(ldsc + bo + aoff + mb * 2048
                                + (kb >> 1) * 8192 + ((((kb & 1) * 32) + ib) ^ amask));
        #pragma unroll
        for (int kb = 0; kb < 4; ++kb)
            bfA[kb] = *(const bf16x8*)(ldsc + bo + boff
                                + (kb >> 1) * 8192 + ((((kb & 1) * 32) + ib) ^ amask));
        if (t + 1 < NT) STAGE(srcB0, t + 1, bo2 + 32768);
        __builtin_amdgcn_s_barrier();
        __builtin_amdgcn_sched_barrier(0);
        __builtin_amdgcn_s_setprio(1);
        #pragma unroll
        for (int mb = 0; mb < 2; ++mb)
            #pragma unroll
            for (int kb = 0; kb < 4; ++kb)
                acc[mb][0] = __builtin_amdgcn_mfma_f32_32x32x16_bf16(
                    af[mb][kb], bfA[kb], acc[mb][0], 0, 0, 0);
        __builtin_amdgcn_s_setprio(0);

        // ---- phase 2: read B(nb1); stage B_hi(t+1); MFMA Q01 ----
        #pragma unroll
        for (int kb = 0; kb < 4; ++kb)
            bfB[kb] = *(const bf16x8*)(ldsc + bo + boff + 2048
                                + (kb >> 1) * 8192 + ((((kb & 1) * 32) + ib) ^ amask));
        if (t + 1 < NT) STAGE(srcB1, t + 1, bo2 + 49152);
        __builtin_amdgcn_s_barrier();
        __builtin_amdgcn_sched_barrier(0);
        __builtin_amdgcn_s_setprio(1);
        #pragma unroll
        for (int mb = 0; mb < 2; ++mb)
            #pragma unroll
            for (int kb = 0; kb < 4; ++kb)
                acc[mb][1] = __builtin_amdgcn_mfma_f32_32x32x16_bf16(
                    af[mb][kb], bfB[kb], acc[mb][1], 0, 0, 0);
        __builtin_amdgcn_s_setprio(0);

        // ---- phase 3: read A(mb2,3); stage A_lo+A_hi(t+2); MFMA Q11+Q10; vmcnt ----
        #pragma unroll
        for (int mb = 0; mb < 2; ++mb)
            #pragma unroll
            for (int kb = 0; kb < 4; ++kb)
                af[mb][kb] = *(const bf16x8*)(ldsc + bo + aoff + (mb + 2) * 2048
                                + (kb >> 1) * 8192 + ((((kb & 1) * 32) + ib) ^ amask));
        if (t + 2 < NT) {
            STAGE(srcA0, t + 2, bo + 0);
            STAGE(srcA1, t + 2, bo + 16384);
        }
        __builtin_amdgcn_s_barrier();
        __builtin_amdgcn_sched_barrier(0);
        __builtin_amdgcn_s_setprio(1);
        #pragma unroll
        for (int mb = 0; mb < 2; ++mb)
            #pragma unroll
            for (int kb = 0; kb < 4; ++kb)
                acc[mb + 2][1] = __builtin_amdgcn_mfma_f32_32x32x16_bf16(
                    af[mb][kb], bfB[kb], acc[mb + 2][1], 0, 0, 0);
        #pragma unroll
        for (int mb = 0; mb < 2; ++mb)
            #pragma unroll
            for (int kb = 0; kb < 4; ++kb)
                acc[mb + 2][0] = __builtin_amdgcn_mfma_f32_32x32x16_bf16(
                    af[mb][kb], bfA[kb], acc[mb + 2][0], 0, 0, 0);
        __builtin_amdgcn_s_setprio(0);
        if (t + 2 < NT)      { asm volatile("s_waitcnt vmcnt(4)" ::: "memory"); }
        else if (t + 1 < NT) { asm volatile("s_waitcnt vmcnt(0)" ::: "memory"); }
        __builtin_amdgcn_s_barrier();
        __builtin_amdgcn_sched_barrier(0);
    }

    // epilogue: 32x32 C/D layout col=lane&31, row=(reg&3)+8*(reg>>2)+4*(lane>>5)
    float bv[2];
    #pragma unroll
    for (int nb = 0; nb < 2; ++nb)
        bv[nb] = bias[bn * 256 + wc * 64 + nb * 32 + l31];
    #pragma unroll
    for (int mb = 0; mb < 4; ++mb) {
        const int rbase = bm * 256 + wr * 128 + mb * 32 + 4 * l5;
        #pragma unroll
        for (int nb = 0; nb < 2; ++nb) {
            const int col = bn * 256 + wc * 64 + nb * 32 + l31;
            #pragma unroll
            for (int r = 0; r < 16; ++r) {
                const int row = rbase + (r & 3) + 8 * (r >> 2);
                C[(size_t)row * N_DIM + col] = acc[mb][nb][r] + bv[nb];
            }
        }
    }
}

// ---------- fallback (ws too small): slow but correct ----------
__global__ __launch_bounds__(256) void fallback_gemm(
        const float* __restrict__ x, const float* __restrict__ w,
        const float* __restrict__ value, const float* __restrict__ mins,
        const float* __restrict__ maxs, const float* __restrict__ bias,
        float* __restrict__ out) {
    const int n = blockIdx.x;
    __shared__ float wrow[K_DIM];
    const int tid = threadIdx.x;
    if (tid < GROUPS_PER_ROW) {
        const int g = tid;
        const float* wp = w + (size_t)n * K_DIM + g * 32;
        const float* vp = value + (size_t)n * K_DIM + g * 32;
        float tw[32];
        float mn = 1e30f, mx = -1e30f;
        #pragma unroll
        for (int j = 0; j < 32; j++) {
            tw[j] = wp[j]; mn = fminf(mn, tw[j]); mx = fmaxf(mx, tw[j]);
        }
        float wmin = mn * mins[n * GROUPS_PER_ROW + g];
        float wmax = mx * maxs[n * GROUPS_PER_ROW + g];
        float scale = fmaxf((wmax - wmin) * (1.0f / 255.0f), 1e-8f);
        float zp = -wmin / scale;
        #pragma unroll
        for (int j = 0; j < 32; j++) {
            float ws_ = tw[j] / scale + zp + vp[j];
            float q = fminf(fmaxf(rintf(ws_), 0.0f), 255.0f);
            wrow[g * 32 + j] = scale * (q - zp);
        }
    }
    __syncthreads();
    const float bv = bias[n];
    for (int m = tid; m < M_DIM; m += 256) {
        const float4* xr = reinterpret_cast<const float4*>(x + (size_t)m * K_DIM);
        const float4* wr4 = reinterpret_cast<const float4*>(wrow);
        float s = 0.f;
        for (int k = 0; k < K_DIM / 4; k++) {
            float4 a = xr[k], b = wr4[k];
            s += a.x * b.x + a.y * b.y + a.z * b.z + a.w * b.w;
        }
        out[(size_t)m * N_DIM + n] = s + bv;
    }
}

extern "C" void kernel_launch(void* const* d_in, const int* in_sizes, int n_in,
                              void* d_out, int out_size, void* d_ws, size_t ws_size,
                              hipStream_t stream) {
    const float* x     = (const float*)d_in[0];
    const float* ow    = (const float*)d_in[1];
    const float* value = (const float*)d_in[2];
    const float* mins  = (const float*)d_in[3];
    const float* maxs  = (const float*)d_in[4];
    const float* bias  = (const float*)d_in[5];
    float* out = (float*)d_out;

    const size_t xb_bytes = (size_t)M_DIM * K_DIM * 2;
    const size_t wb_bytes = (size_t)N_DIM * K_DIM * 2;

    if (ws_size >= xb_bytes + wb_bytes) {
        unsigned short* xb = (unsigned short*)d_ws;
        unsigned short* wb = (unsigned short*)((char*)d_ws + xb_bytes);

        dequant_kernel<<<(N_DIM * GROUPS_PER_ROW) / 256, 256, 0, stream>>>(
            ow, value, mins, maxs, wb);
        xconv_kernel<<<(M_DIM * K_DIM / 8) / 256, 256, 0, stream>>>(x, xb);
        gemm_kernel<<<(M_DIM / 256) * (N_DIM / 256), 512, 0, stream>>>(
            xb, wb, bias, out);
    } else {
        fallback_gemm<<<N_DIM, 256, 0, stream>>>(x, ow, value, mins, maxs, bias, out);
    }
}

// Round 7
// 311.357 us; speedup vs baseline: 1.0328x; 1.0036x over previous
//
#include <hip/hip_runtime.h>

// Problem constants (fixed by setup_inputs)
#define M_DIM 8192      // 4*2048
#define N_DIM 4096      // out_f
#define K_DIM 4096      // in_f
#define GROUPS_PER_ROW 128
#define NT (K_DIM / 64) // 64 K-tiles of BK=64

typedef short bf16x8 __attribute__((ext_vector_type(8)));
typedef float f32x16 __attribute__((ext_vector_type(16)));
typedef unsigned short u16x8 __attribute__((ext_vector_type(8)));

__device__ __forceinline__ unsigned short f2bf(float f) {
    unsigned int u = __float_as_uint(f);
    u += 0x7fffu + ((u >> 16) & 1u);   // round-to-nearest-even
    return (unsigned short)(u >> 16);
}

typedef const __attribute__((address_space(1))) void gvoid_t;
typedef __attribute__((address_space(3))) void lvoid_t;
__device__ __forceinline__ void gload_lds16(const void* g, void* l) {
    __builtin_amdgcn_global_load_lds((gvoid_t*)g, (lvoid_t*)l, 16, 0, 0);
}

// ---------- pass 1: dequantize weight -> bf16 [N][K] ----------
__global__ __launch_bounds__(256) void dequant_kernel(
        const float* __restrict__ w, const float* __restrict__ value,
        const float* __restrict__ mins, const float* __restrict__ maxs,
        unsigned short* __restrict__ wq) {
    int g = blockIdx.x * 256 + threadIdx.x;
    const float4* wp = reinterpret_cast<const float4*>(w + (size_t)g * 32);
    const float4* vp = reinterpret_cast<const float4*>(value + (size_t)g * 32);
    float4 wv[8], vv[8];
    #pragma unroll
    for (int j = 0; j < 8; j++) { wv[j] = wp[j]; vv[j] = vp[j]; }
    float mn = wv[0].x, mx = wv[0].x;
    #pragma unroll
    for (int j = 0; j < 8; j++) {
        mn = fminf(mn, fminf(fminf(wv[j].x, wv[j].y), fminf(wv[j].z, wv[j].w)));
        mx = fmaxf(mx, fmaxf(fmaxf(wv[j].x, wv[j].y), fmaxf(wv[j].z, wv[j].w)));
    }
    float w_min = mn * mins[g];
    float w_max = mx * maxs[g];
    float scale = fmaxf((w_max - w_min) * (1.0f / 255.0f), 1e-8f);
    float zp    = -w_min / scale;
    float rs    = 1.0f / scale;
    unsigned short ob[32];
    #pragma unroll
    for (int j = 0; j < 8; j++) {
        const float* wf = &wv[j].x;
        const float* vf = &vv[j].x;
        #pragma unroll
        for (int c = 0; c < 4; c++) {
            float ws_ = wf[c] * rs + zp + vf[c];
            float q   = fminf(fmaxf(rintf(ws_), 0.0f), 255.0f);
            ob[j * 4 + c] = f2bf(scale * (q - zp));
        }
    }
    u16x8* op = reinterpret_cast<u16x8*>(wq + (size_t)g * 32);
    #pragma unroll
    for (int j = 0; j < 4; j++) {
        u16x8 v;
        #pragma unroll
        for (int c = 0; c < 8; c++) v[c] = ob[j * 8 + c];
        op[j] = v;
    }
}

// ---------- pass 2: x f32 -> bf16 ----------
__global__ __launch_bounds__(256) void xconv_kernel(
        const float* __restrict__ x, unsigned short* __restrict__ xb) {
    int t = blockIdx.x * 256 + threadIdx.x;
    const float4* xp = reinterpret_cast<const float4*>(x) + (size_t)t * 2;
    float4 a = xp[0], b = xp[1];
    u16x8 v;
    v[0] = f2bf(a.x); v[1] = f2bf(a.y); v[2] = f2bf(a.z); v[3] = f2bf(a.w);
    v[4] = f2bf(b.x); v[5] = f2bf(b.y); v[6] = f2bf(b.z); v[7] = f2bf(b.w);
    reinterpret_cast<u16x8*>(xb)[t] = v;
}

// ---------- pass 3: 256x256 8-wave 2-SEGMENT 32x32x16 MFMA GEMM-BT + bias ----------
// C[m][n] = sum_k A[m][k]*B[n][k] + bias[n]
// LDS per 64KB buffer: A [2 half(128r)][2 kk-panel][128 rows][64B] at 0, B at +32KB.
// Wide swizzle (round-6 verified, conflicts=0): phys = L ^ ((L>>9&1)<<4) ^ ((L>>10&1)<<5).
// Round-7 structure change: only TWO barriers per K-tile; no lgkmcnt(0)/sched_barrier
// between reads and MFMA — compiler emits fine-grained lgkmcnt(N), and 2-waves/SIMD
// skew overlaps the LDS pipe (the binding 2816cyc/tile floor) with the MFMA pipe.
// Counted vmcnt(4) at tile end: leaves only A(t+2) in flight; all tile-t+1 data landed.
__global__ __launch_bounds__(512, 2) void gemm_kernel(
        const unsigned short* __restrict__ A, const unsigned short* __restrict__ B,
        const float* __restrict__ bias, float* __restrict__ C) {
    __shared__ __align__(128) char lds[131072];

    const int tid  = threadIdx.x;
    const int lane = tid & 63;
    const int w    = tid >> 6;          // 0..7
    const int wr   = w >> 2;            // 0..1 (M split: 128 rows)
    const int wc   = w & 3;             // 0..3 (N split: 64 cols)
    const int l31  = lane & 31, l5 = lane >> 5;

    // T1: bijective XCD swizzle (grid=512, 512%8==0)
    const int bid = blockIdx.x;
    const int swz = (bid & 7) * 64 + (bid >> 3);
    const int bm  = swz >> 4;           // 0..31
    const int bn  = swz & 15;           // 0..15

    // read-side swizzle mask: row bits 3,4 (= l31 bits 3,4) -> col bits 4,5
    const int amask = (l31 & 24) << 1;  // bits 4,5
    const int ib    = l5 * 16;          // k-sub half (bit 4)

    // region bases (byte offsets into half-buffer); row term l31*64 (bits >=6)
    const int aoff = wr * 16384 + l31 * 64;
    const int boff = 32768 + (wc >> 1) * 16384 + (wc & 1) * 4096 + l31 * 64;

    // staging: linear 16B chunks; source address inverse-swizzled
    // (bits 9,10 -> bits 4,5; involution)
    const int c0  = tid * 16;
    const int c1  = 8192 + tid * 16;
    const int lb0 = c0 ^ (((c0 >> 9) & 1) << 4) ^ (((c0 >> 10) & 1) << 5);
    const int lb1 = c1 ^ (((c1 >> 9) & 1) << 4) ^ (((c1 >> 10) & 1) << 5);
    const int so0 = ((lb0 >> 6) & 127) * (K_DIM * 2) + (lb0 >> 13) * 64 + (lb0 & 63);
    const int so1 = ((lb1 >> 6) & 127) * (K_DIM * 2) + (lb1 >> 13) * 64 + (lb1 & 63);

    const char* srcA0 = (const char*)A + (size_t)(bm * 256 +   0) * (K_DIM * 2);
    const char* srcA1 = (const char*)A + (size_t)(bm * 256 + 128) * (K_DIM * 2);
    const char* srcB0 = (const char*)B + (size_t)(bn * 256 +   0) * (K_DIM * 2);
    const char* srcB1 = (const char*)B + (size_t)(bn * 256 + 128) * (K_DIM * 2);

    char* ldsc = (char*)lds;
    auto STAGE = [&](const char* src, int tt, int regionOff) {
        gload_lds16(src + (size_t)tt * 128 + so0, ldsc + regionOff + c0);
        gload_lds16(src + (size_t)tt * 128 + so1, ldsc + regionOff + c1);
    };

    f32x16 acc[4][2] = {};          // [mb 0..3][nb 0..1] = 128 acc regs
    bf16x8 af[2][4], bfA[4], bfB[4];

    // fragment byte offset (compile-time kb):
    //   FR(kb) = (kb>>1)*8192 + (((kb&1)*32 + ib) ^ amask)

    // prologue: tile0 all 4 half-tiles -> buf0; tile1 A halves -> buf1
    STAGE(srcA0, 0, 0);
    STAGE(srcA1, 0, 16384);
    STAGE(srcB0, 0, 32768);
    STAGE(srcB1, 0, 49152);
    STAGE(srcA0, 1, 65536);
    STAGE(srcA1, 1, 65536 + 16384);
    asm volatile("s_waitcnt vmcnt(4)" ::: "memory");
    __builtin_amdgcn_s_barrier();
    __builtin_amdgcn_sched_barrier(0);

    #pragma unroll 2
    for (int t = 0; t < NT; ++t) {
        const int bo  = (t & 1) << 16;
        const int bo2 = bo ^ 65536;

        // ==== segment 1: stage B(t+1)->bo2; read A(mb0,1)+B(nb0,1); MFMA Q00+Q01 ====
        if (t + 1 < NT) {
            STAGE(srcB0, t + 1, bo2 + 32768);
            STAGE(srcB1, t + 1, bo2 + 49152);
        }
        #pragma unroll
        for (int mb = 0; mb < 2; ++mb)
            #pragma unroll
            for (int kb = 0; kb < 4; ++kb)
                af[mb][kb] = *(const bf16x8*)(ldsc + bo + aoff + mb * 2048
                                + (kb >> 1) * 8192 + ((((kb & 1) * 32) + ib) ^ amask));
        #pragma unroll
        for (int kb = 0; kb < 4; ++kb)
            bfA[kb] = *(const bf16x8*)(ldsc + bo + boff
                                + (kb >> 1) * 8192 + ((((kb & 1) * 32) + ib) ^ amask));
        #pragma unroll
        for (int kb = 0; kb < 4; ++kb)
            bfB[kb] = *(const bf16x8*)(ldsc + bo + boff + 2048
                                + (kb >> 1) * 8192 + ((((kb & 1) * 32) + ib) ^ amask));
        __builtin_amdgcn_s_setprio(1);
        #pragma unroll
        for (int mb = 0; mb < 2; ++mb)
            #pragma unroll
            for (int kb = 0; kb < 4; ++kb)
                acc[mb][0] = __builtin_amdgcn_mfma_f32_32x32x16_bf16(
                    af[mb][kb], bfA[kb], acc[mb][0], 0, 0, 0);
        #pragma unroll
        for (int mb = 0; mb < 2; ++mb)
            #pragma unroll
            for (int kb = 0; kb < 4; ++kb)
                acc[mb][1] = __builtin_amdgcn_mfma_f32_32x32x16_bf16(
                    af[mb][kb], bfB[kb], acc[mb][1], 0, 0, 0);
        __builtin_amdgcn_s_setprio(0);
        __builtin_amdgcn_s_barrier();
        __builtin_amdgcn_sched_barrier(0);

        // ==== segment 2: read A(mb2,3); stage A(t+2)->bo; MFMA Q10+Q11; vmcnt ====
        #pragma unroll
        for (int mb = 0; mb < 2; ++mb)
            #pragma unroll
            for (int kb = 0; kb < 4; ++kb)
                af[mb][kb] = *(const bf16x8*)(ldsc + bo + aoff + (mb + 2) * 2048
                                + (kb >> 1) * 8192 + ((((kb & 1) * 32) + ib) ^ amask));
        if (t + 2 < NT) {
            STAGE(srcA0, t + 2, bo + 0);
            STAGE(srcA1, t + 2, bo + 16384);
        }
        __builtin_amdgcn_s_setprio(1);
        #pragma unroll
        for (int mb = 0; mb < 2; ++mb)
            #pragma unroll
            for (int kb = 0; kb < 4; ++kb)
                acc[mb + 2][0] = __builtin_amdgcn_mfma_f32_32x32x16_bf16(
                    af[mb][kb], bfA[kb], acc[mb + 2][0], 0, 0, 0);
        #pragma unroll
        for (int mb = 0; mb < 2; ++mb)
            #pragma unroll
            for (int kb = 0; kb < 4; ++kb)
                acc[mb + 2][1] = __builtin_amdgcn_mfma_f32_32x32x16_bf16(
                    af[mb][kb], bfB[kb], acc[mb + 2][1], 0, 0, 0);
        __builtin_amdgcn_s_setprio(0);
        if (t + 2 < NT)      { asm volatile("s_waitcnt vmcnt(4)" ::: "memory"); }
        else if (t + 1 < NT) { asm volatile("s_waitcnt vmcnt(0)" ::: "memory"); }
        __builtin_amdgcn_s_barrier();
        __builtin_amdgcn_sched_barrier(0);
    }

    // epilogue: 32x32 C/D layout col=lane&31, row=(reg&3)+8*(reg>>2)+4*(lane>>5)
    float bv[2];
    #pragma unroll
    for (int nb = 0; nb < 2; ++nb)
        bv[nb] = bias[bn * 256 + wc * 64 + nb * 32 + l31];
    #pragma unroll
    for (int mb = 0; mb < 4; ++mb) {
        const int rbase = bm * 256 + wr * 128 + mb * 32 + 4 * l5;
        #pragma unroll
        for (int nb = 0; nb < 2; ++nb) {
            const int col = bn * 256 + wc * 64 + nb * 32 + l31;
            #pragma unroll
            for (int r = 0; r < 16; ++r) {
                const int row = rbase + (r & 3) + 8 * (r >> 2);
                C[(size_t)row * N_DIM + col] = acc[mb][nb][r] + bv[nb];
            }
        }
    }
}

// ---------- fallback (ws too small): slow but correct ----------
__global__ __launch_bounds__(256) void fallback_gemm(
        const float* __restrict__ x, const float* __restrict__ w,
        const float* __restrict__ value, const float* __restrict__ mins,
        const float* __restrict__ maxs, const float* __restrict__ bias,
        float* __restrict__ out) {
    const int n = blockIdx.x;
    __shared__ float wrow[K_DIM];
    const int tid = threadIdx.x;
    if (tid < GROUPS_PER_ROW) {
        const int g = tid;
        const float* wp = w + (size_t)n * K_DIM + g * 32;
        const float* vp = value + (size_t)n * K_DIM + g * 32;
        float tw[32];
        float mn = 1e30f, mx = -1e30f;
        #pragma unroll
        for (int j = 0; j < 32; j++) {
            tw[j] = wp[j]; mn = fminf(mn, tw[j]); mx = fmaxf(mx, tw[j]);
        }
        float wmin = mn * mins[n * GROUPS_PER_ROW + g];
        float wmax = mx * maxs[n * GROUPS_PER_ROW + g];
        float scale = fmaxf((wmax - wmin) * (1.0f / 255.0f), 1e-8f);
        float zp = -wmin / scale;
        #pragma unroll
        for (int j = 0; j < 32; j++) {
            float ws_ = tw[j] / scale + zp + vp[j];
            float q = fminf(fmaxf(rintf(ws_), 0.0f), 255.0f);
            wrow[g * 32 + j] = scale * (q - zp);
        }
    }
    __syncthreads();
    const float bv = bias[n];
    for (int m = tid; m < M_DIM; m += 256) {
        const float4* xr = reinterpret_cast<const float4*>(x + (size_t)m * K_DIM);
        const float4* wr4 = reinterpret_cast<const float4*>(wrow);
        float s = 0.f;
        for (int k = 0; k < K_DIM / 4; k++) {
            float4 a = xr[k], b = wr4[k];
            s += a.x * b.x + a.y * b.y + a.z * b.z + a.w * b.w;
        }
        out[(size_t)m * N_DIM + n] = s + bv;
    }
}

extern "C" void kernel_launch(void* const* d_in, const int* in_sizes, int n_in,
                              void* d_out, int out_size, void* d_ws, size_t ws_size,
                              hipStream_t stream) {
    const float* x     = (const float*)d_in[0];
    const float* ow    = (const float*)d_in[1];
    const float* value = (const float*)d_in[2];
    const float* mins  = (const float*)d_in[3];
    const float* maxs  = (const float*)d_in[4];
    const float* bias  = (const float*)d_in[5];
    float* out = (float*)d_out;

    const size_t xb_bytes = (size_t)M_DIM * K_DIM * 2;
    const size_t wb_bytes = (size_t)N_DIM * K_DIM * 2;

    if (ws_size >= xb_bytes + wb_bytes) {
        unsigned short* xb = (unsigned short*)d_ws;
        unsigned short* wb = (unsigned short*)((char*)d_ws + xb_bytes);

        dequant_kernel<<<(N_DIM * GROUPS_PER_ROW) / 256, 256, 0, stream>>>(
            ow, value, mins, maxs, wb);
        xconv_kernel<<<(M_DIM * K_DIM / 8) / 256, 256, 0, stream>>>(x, xb);
        gemm_kernel<<<(M_DIM / 256) * (N_DIM / 256), 512, 0, stream>>>(
            xb, wb, bias, out);
    } else {
        fallback_gemm<<<N_DIM, 256, 0, stream>>>(x, ow, value, mins, maxs, bias, out);
    }
}